// Round 1
// baseline (503.124 us; speedup 1.0000x reference)
//
#include <hip/hip_runtime.h>
#include <hip/hip_bf16.h>

#define NN   8192
#define INF_ 256
#define OF   128
#define EMBD 16
#define QB   32
#define JB   128
#define NST  (NN / JB)

typedef __attribute__((ext_vector_type(4))) float f32x4;
typedef __attribute__((ext_vector_type(8))) short s16x8;

__device__ __forceinline__ unsigned short f2bf(float x) {
  unsigned u = __builtin_bit_cast(unsigned, x);
  return (unsigned short)((u + 0x7FFFu + ((u >> 16) & 1u)) >> 16);
}

__device__ __forceinline__ float fexp2(float x) {
#if __has_builtin(__builtin_amdgcn_exp2f)
  return __builtin_amdgcn_exp2f(x);
#else
  return exp2f(x);
#endif
}

// ---- K1: hh = eps + h @ W_fc  (f32) ----
__global__ __launch_bounds__(256) void k_hh(const float* __restrict__ h,
                                            const float* __restrict__ eps,
                                            const float* __restrict__ Wfc,
                                            float* __restrict__ hh) {
  const int o  = threadIdx.x & (OF - 1);
  const int rh = threadIdx.x >> 7;           // 0..1
  const int i0 = blockIdx.x * 8 + rh * 4;    // 8 rows / block
  float a0 = eps[(size_t)(i0 + 0) * OF + o];
  float a1 = eps[(size_t)(i0 + 1) * OF + o];
  float a2 = eps[(size_t)(i0 + 2) * OF + o];
  float a3 = eps[(size_t)(i0 + 3) * OF + o];
  const float* h0 = h + (size_t)(i0 + 0) * INF_;
  const float* h1 = h + (size_t)(i0 + 1) * INF_;
  const float* h2 = h + (size_t)(i0 + 2) * INF_;
  const float* h3 = h + (size_t)(i0 + 3) * INF_;
#pragma unroll 4
  for (int kk = 0; kk < INF_; ++kk) {
    const float wv = Wfc[(size_t)kk * OF + o];
    a0 = fmaf(h0[kk], wv, a0);
    a1 = fmaf(h1[kk], wv, a1);
    a2 = fmaf(h2[kk], wv, a2);
    a3 = fmaf(h3[kk], wv, a3);
  }
  hh[(size_t)(i0 + 0) * OF + o] = a0;
  hh[(size_t)(i0 + 1) * OF + o] = a1;
  hh[(size_t)(i0 + 2) * OF + o] = a2;
  hh[(size_t)(i0 + 3) * OF + o] = a3;
}

// ---- K2: k' = (hh @ W_k) * log2(e), q = hh @ W_q ----
__global__ __launch_bounds__(256) void k_kq(const float* __restrict__ hh,
                                            const float* __restrict__ Wk,
                                            const float* __restrict__ Wq,
                                            float* __restrict__ kp,
                                            float* __restrict__ qp) {
  const int t = blockIdx.x * 256 + threadIdx.x;   // 8192*32 total
  const int i = t >> 5;
  const int c = t & 31;
  const int e = c & 15;
  const float* W = (c < 16) ? Wk : Wq;
  const float* hr = hh + (size_t)i * OF;
  float s0 = 0.f, s1 = 0.f;
#pragma unroll 8
  for (int o = 0; o < OF; o += 2) {
    s0 = fmaf(hr[o], W[o * EMBD + e], s0);
    s1 = fmaf(hr[o + 1], W[(o + 1) * EMBD + e], s1);
  }
  const float s = s0 + s1;
  if (c < 16) kp[(size_t)i * EMBD + e] = s * 1.4426950408889634f;
  else        qp[(size_t)i * EMBD + e] = s;
}

// ---- K3: hhT (bf16) [OF][NN] = transpose(hh) ----
__global__ __launch_bounds__(256) void k_tr(const float* __restrict__ hh,
                                            short* __restrict__ hhT) {
  __shared__ float tile[64][65];
  const int i0 = blockIdx.x * 64;
  const int o0 = blockIdx.y * 64;
  const int c = threadIdx.x & 63;
  const int r = threadIdx.x >> 6;
#pragma unroll
  for (int rr = 0; rr < 16; ++rr) {
    const int ii = rr * 4 + r;
    tile[ii][c] = hh[(size_t)(i0 + ii) * OF + o0 + c];
  }
  __syncthreads();
#pragma unroll
  for (int rr = 0; rr < 16; ++rr) {
    const int oo = rr * 4 + r;
    hhT[(size_t)(o0 + oo) * NN + i0 + c] = (short)f2bf(tile[c][oo]);
  }
}

// ---- K4: fused masked-attention pass ----
// out[i,:] = sum_j a_str[i,j]*2^(s_ij - m_i) * hh[j,:] / sum_j a_str[i,j]*2^(s_ij - m_i)
__global__ __launch_bounds__(512, 1) void k_attn(const float* __restrict__ Astr,
                                                 const float* __restrict__ kp,
                                                 const float* __restrict__ qp,
                                                 const short* __restrict__ hhT,
                                                 float* __restrict__ out) {
  __shared__ __align__(16) float qbuf[2][JB * 20];   // [j][20] padded, f32
  __shared__ __align__(16) short wbuf[2][QB * JB];   // bf16 weights, XOR-swizzled
  __shared__ float fscale[2][QB];
  __shared__ float dfin[QB];

  const int tid = threadIdx.x;
  const int l   = tid & 63;
  const int w   = tid >> 6;
  const int row = tid >> 4;   // s-role: 0..31
  const int g   = tid & 15;   // s-role: j-chunk
  const int rt  = w >> 2;     // mfma-role: row-tile 0..1
  const int ctp = w & 3;      // mfma-role: 32-col group
  const int h4  = l >> 4;
  const int ln  = l & 15;
  const int rb  = blockIdx.x * QB;
  const int jr  = tid >> 2;   // q-stage role: 0..127
  const int e4  = tid & 3;

  float kreg[16];
  {
    const f32x4* kv = (const f32x4*)(kp + (size_t)(rb + row) * EMBD);
#pragma unroll
    for (int i = 0; i < 4; ++i) {
      f32x4 v = kv[i];
      kreg[i * 4 + 0] = v.x; kreg[i * 4 + 1] = v.y;
      kreg[i * 4 + 2] = v.z; kreg[i * 4 + 3] = v.w;
    }
  }
  f32x4 acc0 = {0.f, 0.f, 0.f, 0.f};
  f32x4 acc1 = {0.f, 0.f, 0.f, 0.f};
  float mrun = -1e30f;
  float dpart = 0.f;

  const size_t arow = (size_t)(rb + row) * NN;
  const int swz_w = (row & 7) << 3;
  const int ra    = rt * 16 + ln;
  const int swz_r = (ra & 7) << 3;

  // prologue: stage q tile 0, prefetch a_str tile 0
  {
    f32x4 v = *(const f32x4*)(qp + (size_t)jr * EMBD + e4 * 4);
    *(f32x4*)&qbuf[0][jr * 20 + e4 * 4] = v;
  }
  float aA[8], aB[8];
#pragma unroll
  for (int jj = 0; jj < 8; ++jj) aA[jj] = Astr[arow + g + 16 * jj];
  __syncthreads();

  auto STEP = [&](int t, float (&acur)[8], float (&anxt)[8], int par) {
    const int jb = t * JB;
    const int tn = (t + 1 < NST) ? (t + 1) : 0;
    const int jn = tn * JB;
    // phase 1a: next q tile -> regs
    f32x4 qv = *(const f32x4*)(qp + (size_t)(jn + jr) * EMBD + e4 * 4);
    // phase 1b: B-fragments for current tile (L2-resident hhT)
    s16x8 bfr[2][4];
#pragma unroll
    for (int cc = 0; cc < 2; ++cc) {
      const size_t bbase = (size_t)(ctp * 32 + cc * 16 + ln) * NN + jb + h4 * 8;
#pragma unroll
      for (int kt = 0; kt < 4; ++kt)
        bfr[cc][kt] = *(const s16x8*)(hhT + bbase + kt * 32);
    }
    // phase 1c: a_str prefetch for next tile (HBM stream)
#pragma unroll
    for (int jj = 0; jj < 8; ++jj) anxt[jj] = Astr[arow + jn + g + 16 * jj];
    // phase 2: scores (f32, log2-units; thread's j = g + 16*jj)
    float s[8];
#pragma unroll
    for (int jj = 0; jj < 8; ++jj) {
      const float* qr = &qbuf[par][(g + 16 * jj) * 20];
      const f32x4 q0 = *(const f32x4*)(qr + 0);
      const f32x4 q1 = *(const f32x4*)(qr + 4);
      const f32x4 q2 = *(const f32x4*)(qr + 8);
      const f32x4 q3 = *(const f32x4*)(qr + 12);
      float t0 = kreg[0] * q0.x, t1 = kreg[1] * q0.y;
      t0 = fmaf(kreg[2],  q0.z, t0); t1 = fmaf(kreg[3],  q0.w, t1);
      t0 = fmaf(kreg[4],  q1.x, t0); t1 = fmaf(kreg[5],  q1.y, t1);
      t0 = fmaf(kreg[6],  q1.z, t0); t1 = fmaf(kreg[7],  q1.w, t1);
      t0 = fmaf(kreg[8],  q2.x, t0); t1 = fmaf(kreg[9],  q2.y, t1);
      t0 = fmaf(kreg[10], q2.z, t0); t1 = fmaf(kreg[11], q2.w, t1);
      t0 = fmaf(kreg[12], q3.x, t0); t1 = fmaf(kreg[13], q3.y, t1);
      t0 = fmaf(kreg[14], q3.z, t0); t1 = fmaf(kreg[15], q3.w, t1);
      s[jj] = t0 + t1;
    }
    // phase 3: online max + weights
    float tmax = s[0];
#pragma unroll
    for (int jj = 1; jj < 8; ++jj) tmax = fmaxf(tmax, s[jj]);
    tmax = fmaxf(tmax, __shfl_xor(tmax, 1, 16));
    tmax = fmaxf(tmax, __shfl_xor(tmax, 2, 16));
    tmax = fmaxf(tmax, __shfl_xor(tmax, 4, 16));
    tmax = fmaxf(tmax, __shfl_xor(tmax, 8, 16));
    const float mnew = fmaxf(mrun, tmax);
    const float f = fexp2(mrun - mnew);
    mrun = mnew;
    dpart *= f;
#pragma unroll
    for (int jj = 0; jj < 8; ++jj) {
      const float wv = acur[jj] * fexp2(s[jj] - mnew);
      dpart += wv;
      wbuf[par][row * JB + ((g + 16 * jj) ^ swz_w)] = (short)f2bf(wv);
    }
    if (g == 0) fscale[par][row] = f;
    // phase 3.5: complete q stage into other buffer
    *(f32x4*)&qbuf[par ^ 1][jr * 20 + e4 * 4] = qv;
    __syncthreads();
    // phase 5: rescale accumulators, then PV MFMA
#pragma unroll
    for (int r = 0; r < 4; ++r) {
      const float fr = fscale[par][rt * 16 + 4 * h4 + r];
      acc0[r] *= fr;
      acc1[r] *= fr;
    }
    s16x8 afr[4];
#pragma unroll
    for (int kt = 0; kt < 4; ++kt)
      afr[kt] = *(const s16x8*)&wbuf[par][ra * JB + ((kt * 32 + h4 * 8) ^ swz_r)];
#pragma unroll
    for (int kt = 0; kt < 4; ++kt) {
      acc0 = __builtin_amdgcn_mfma_f32_16x16x32_bf16(afr[kt], bfr[0][kt], acc0, 0, 0, 0);
      acc1 = __builtin_amdgcn_mfma_f32_16x16x32_bf16(afr[kt], bfr[1][kt], acc1, 0, 0, 0);
    }
  };

  for (int t = 0; t < NST; t += 2) {
    STEP(t,     aA, aB, 0);
    STEP(t + 1, aB, aA, 1);
  }

  // epilogue: reduce denominator, divide, store
  float d = dpart;
  d += __shfl_xor(d, 1, 16);
  d += __shfl_xor(d, 2, 16);
  d += __shfl_xor(d, 4, 16);
  d += __shfl_xor(d, 8, 16);
  if (g == 0) dfin[row] = d;
  __syncthreads();
#pragma unroll
  for (int r = 0; r < 4; ++r) {
    const int lrow = rt * 16 + 4 * h4 + r;
    const float inv = 1.0f / dfin[lrow];
    float* orow = out + (size_t)(rb + lrow) * OF + ctp * 32 + ln;
    orow[0]  = acc0[r] * inv;
    orow[16] = acc1[r] * inv;
  }
}

extern "C" void kernel_launch(void* const* d_in, const int* in_sizes, int n_in,
                              void* d_out, int out_size, void* d_ws, size_t ws_size,
                              hipStream_t stream) {
  const float* h   = (const float*)d_in[0];
  const float* eps = (const float*)d_in[1];
  const float* As  = (const float*)d_in[2];
  const float* Wfc = (const float*)d_in[3];
  const float* Wk  = (const float*)d_in[4];
  const float* Wq  = (const float*)d_in[5];
  float* out = (float*)d_out;

  char* ws = (char*)d_ws;
  float* hh  = (float*)(ws);                              // 4 MB
  short* hhT = (short*)(ws + (4u << 20));                 // 2 MB
  float* kp  = (float*)(ws + (6u << 20));                 // 512 KB
  float* qp  = (float*)(ws + (6u << 20) + (512u << 10));  // 512 KB

  k_hh<<<NN / 8, 256, 0, stream>>>(h, eps, Wfc, hh);
  k_kq<<<(NN * 32) / 256, 256, 0, stream>>>(hh, Wk, Wq, kp, qp);
  k_tr<<<dim3(NN / 64, OF / 64), 256, 0, stream>>>(hh, hhT);
  k_attn<<<NN / QB, 512, 0, stream>>>(As, kp, qp, hhT, out);
}